// Round 16
// baseline (188.909 us; speedup 1.0000x reference)
//
#include <hip/hip_runtime.h>
#include <hip/hip_bf16.h>

// Multi-head attention: x[16,1024,768] fp32, W_qkv[768,2304], b_qkv[2304],
// W_out[768,768], b_out[768] -> out[16,1024,768] fp32.
// Pipeline:
//   1) cvt_x: x -> bf16
//   2) tcvt:  W_qkv, W_out -> transposed bf16
//   3) gemm2<0>: qkv = x @ W_qkv + b; BM256xBN128xBK32, triple-buffered LDS,
//      2 blocks/CU, one wait+barrier per K-tile, RELAXED intra-iteration
//      scheduling (ds_reads/glds co-schedule with MFMA clusters)
//   4) vtrans: V columns of qkvb -> Vt [pair][96][1024]
//   5) attn: 32x32 MFMA, sigma-permuted padded K LDS (round-13 verified)
//   6) gemm2<1>: out = attn @ W_out + b_out -> fp32

#define DEVINL __device__ __forceinline__

typedef __attribute__((ext_vector_type(8))) short s16x8;
typedef __attribute__((ext_vector_type(4))) short s16x4;
typedef __attribute__((ext_vector_type(4))) float f32x4;
typedef __attribute__((ext_vector_type(16))) float f32x16;

DEVINL short f2bf(float f) {
  union { float f; unsigned u; } c; c.f = f;
  unsigned r = c.u + 0x7FFFu + ((c.u >> 16) & 1u);
  return (short)(r >> 16);
}
DEVINL float asf(unsigned u) {
  union { unsigned u; float f; } c; c.u = u; return c.f;
}
// truncating pack (P-weights only; lsum uses the SAME truncated values)
DEVINL unsigned pack2(float a, float b) {
  union { float f; unsigned u; } ca, cb; ca.f = a; cb.f = b;
  return (ca.u >> 16) | (cb.u & 0xffff0000u);
}
DEVINL int swap23(int k) { return (k & ~12) | ((k & 4) << 1) | ((k & 8) >> 1); }

DEVINL void gload_lds16(const short* g, short* lds) {
  __builtin_amdgcn_global_load_lds((const __attribute__((address_space(1))) void*)g,
                                   (__attribute__((address_space(3))) void*)lds, 16, 0, 0);
}

// ---------------- conversion kernels ----------------

__global__ void cvt_x_kernel(const float* __restrict__ in, short* __restrict__ out) {
  int i = blockIdx.x * 256 + threadIdx.x;
  float4 v = ((const float4*)in)[i];
  s16x4 o = { f2bf(v.x), f2bf(v.y), f2bf(v.z), f2bf(v.w) };
  *(s16x4*)(out + (size_t)i * 4) = o;
}

__global__ void tcvt_kernel(const float* __restrict__ in, short* __restrict__ out, int R, int C) {
  __shared__ float t[32][33];
  int tx = threadIdx.x & 31, ty = threadIdx.x >> 5;
  int r0 = blockIdx.y * 32, c0 = blockIdx.x * 32;
#pragma unroll
  for (int i = 0; i < 4; i++) {
    int r = ty + i * 8;
    t[r][tx] = in[(size_t)(r0 + r) * C + c0 + tx];
  }
  __syncthreads();
#pragma unroll
  for (int i = 0; i < 4; i++) {
    int r = ty + i * 8;
    out[(size_t)(c0 + r) * R + r0 + tx] = f2bf(t[tx][r]);
  }
}

// V region of qkvb [16384][2304] -> Vt [pair][96][1024] bf16
__global__ void vtrans_kernel(const short* __restrict__ qkvb, short* __restrict__ out) {
  __shared__ short t[32][34];
  int tx = threadIdx.x & 31, ty = threadIdx.x >> 5;
  int d0 = blockIdx.x * 32, n0 = blockIdx.y * 32;
  int pair = blockIdx.z;
  int b = pair >> 3, h = pair & 7;
#pragma unroll
  for (int i = 0; i < 4; i++) {
    int r = ty + i * 8;
    t[r][tx] = qkvb[(size_t)(b * 1024 + n0 + r) * 2304 + 1536 + h * 96 + d0 + tx];
  }
  __syncthreads();
  size_t obase = (size_t)pair * 96 * 1024;
#pragma unroll
  for (int i = 0; i < 4; i++) {
    int r = ty + i * 8;
    out[obase + (size_t)(d0 + r) * 1024 + n0 + tx] = t[tx][r];
  }
}

// ---------------- GEMM BM=256, BN=128, BK=32, 8 waves, 2 blocks/CU ----------------
// Triple-buffered (tile T staged during iteration T-2). ONE vmcnt wait + ONE
// barrier per K-tile. Scheduling RELAXED inside the iteration: no sched_barrier
// after MFMA clusters, so the compiler interleaves the q1 ds_reads and the
// kt+2 glds with the MFMA issue stream (loads are compiler-tracked; rule-18's
// fence applies only to inline-asm ds_reads). Fences kept: asm volatile WAITV
// (vmcnt ledger intact: all 3 kt+2 stores precede the wait in program order)
// and sched_barrier-wrapped s_barrier.
// MODE 0: bias + q-scale(log2e), bf16 -> qkvb[M][2304] via LDS relayout.
// MODE 1: bias, fp32 [M][768] direct.

template <int MODE>
__global__ __launch_bounds__(512, 4) void gemm2(const short* __restrict__ A, const short* __restrict__ Bt,
                                                const float* __restrict__ bias, int K, int nTn,
                                                short* __restrict__ qkvb, float* __restrict__ outf) {
  __shared__ short lds[36864];          // 72KB: A 3x2x4096 + B 3x4096; MODE0 epilogue 64KB
  short* const ldsA = lds;              // [3 buf][2 q][4096]
  short* const ldsB = lds + 24576;      // [3 buf][4096]
  const int tid = threadIdx.x;
  const int l = tid & 63, w = tid >> 6;
  const int lo = l & 15, hi = l >> 4;
  const int wm = w >> 1, wn = w & 1;

  // XCD-aware bijective swizzle (gridDim.x % 8 == 0)
  int cpx = gridDim.x >> 3;
  int bid = blockIdx.x;
  int swz = (bid & 7) * cpx + (bid >> 3);
  int tm = swz / nTn, tn = swz - tm * nTn;

  const int NKT = K >> 5;

  // staging source (pair-swizzled): thread -> line L, slot s7
  const int Ls = tid >> 3, s7 = tid & 7;
  const int pS = (s7 >> 2) & 1;
  const int cS = (s7 & 3) ^ (Ls & 3);
  const int rho = 2 * Ls + pS;                      // region-row / col index [0,128)
  const int gA = ((rho >> 5) << 6) + (rho & 31);    // A row in tile (q adds +32)
  const short* aS0 = A + (size_t)(tm * 256 + gA) * K + cS * 8;
  const short* aS1 = aS0 + (size_t)32 * K;
  const short* bS = Bt + (size_t)(tn * 128 + rho) * K + cS * 8;

#define ST_A(j, q, bs) gload_lds16(((q) ? aS1 : aS0) + (j) * 32, ldsA + ((bs) * 2 + (q)) * 4096 + tid * 8)
#define ST_B(j, bs)    gload_lds16(bS + (j) * 32, ldsB + (bs) * 4096 + tid * 8)

  const int LaBase = wm * 16 + (lo >> 1);   // + mi*8
  const int LbBase = wn * 32 + (lo >> 1);   // + b*8
  const int pp = (lo & 1) << 2;

  f32x4 acc[4][4] = {};

#define RD_A(AF, bc, qm) do {                                                    \
    const short* base_ = ldsA + ((bc) * 2 + (qm)) * 4096;                        \
    _Pragma("unroll") for (int mi = 0; mi < 2; mi++) {                           \
      int La_ = LaBase + mi * 8;                                                 \
      AF[mi] = *(const s16x8*)(base_ + La_ * 64 + (((hi ^ (La_ & 3)) + pp) << 3)); } } while (0)
#define RD_B(BF, bc) do {                                                        \
    const short* base_ = ldsB + (bc) * 4096;                                     \
    _Pragma("unroll") for (int b = 0; b < 4; b++) {                              \
      int Lb_ = LbBase + b * 8;                                                  \
      BF[b] = *(const s16x8*)(base_ + Lb_ * 64 + (((hi ^ (Lb_ & 3)) + pp) << 3)); } } while (0)

// NOTE: no sched_barrier here — let ds_reads/glds interleave with MFMA issue.
#define MM8(a0, AF, BF) do {                                                     \
    __builtin_amdgcn_s_setprio(1);                                               \
    _Pragma("unroll") for (int mi = 0; mi < 2; mi++)                             \
      _Pragma("unroll") for (int b = 0; b < 4; b++)                              \
        acc[(a0) + mi][b] = __builtin_amdgcn_mfma_f32_16x16x32_bf16(             \
            AF[mi], BF[b], acc[(a0) + mi][b], 0, 0, 0);                          \
    __builtin_amdgcn_s_setprio(0); } while (0)

#define WAITV(n) asm volatile("s_waitcnt vmcnt(" #n ")" ::: "memory")
#define BARR() do { __builtin_amdgcn_sched_barrier(0); __builtin_amdgcn_s_barrier(); \
                    __builtin_amdgcn_sched_barrier(0); } while (0)

  // prologue: tiles 0 and 1 staged fully (tile order preserved for vmcnt)
  ST_A(0, 0, 0); ST_B(0, 0); ST_A(0, 1, 0);
  ST_A(1, 0, 1); ST_B(1, 1); ST_A(1, 1, 1);
  WAITV(3);      // tile 0's three loads retired
  __builtin_amdgcn_s_barrier();

  s16x8 af[2], bf[4];
  int bc = 0;
#pragma unroll 1
  for (int kt = 0; kt < NKT; kt++) {
    int bs = (bc == 0) ? 2 : bc - 1;        // (kt+2) % 3
    RD_A(af, bc, 0);
    RD_B(bf, bc);
    if (kt + 2 < NKT) { ST_A(kt + 2, 0, bs); ST_B(kt + 2, bs); }
    MM8(0, af, bf);
    RD_A(af, bc, 1);
    if (kt + 2 < NKT) ST_A(kt + 2, 1, bs);
    MM8(2, af, bf);
    if (kt + 2 < NKT) {
      WAITV(3);                 // retires tile kt+1's loads (3 newest = tile kt+2)
    } else if (kt + 2 == NKT) {
      WAITV(0);                 // tail: no newer loads; drain tile NKT-1 fully
    }
    BARR();
    bc = (bc == 2) ? 0 : bc + 1;
  }
#undef ST_A
#undef ST_B
#undef RD_A
#undef RD_B
#undef MM8
#undef WAITV
#undef BARR

  if (MODE == 0) {
    // acc -> lds[256][128] bf16 (bias + q-scale), then coalesced b128 stores
    const float qscale = 0.14724444757204526f;  // 96^-0.5 * log2(e)
    __syncthreads();
#pragma unroll
    for (int b = 0; b < 4; b++) {
      int colr = wn * 64 + b * 16 + lo;
      int coln = tn * 128 + colr;
      float bv = bias[coln];
      float scl = (coln < 768) ? qscale : 1.0f;
#pragma unroll
      for (int a = 0; a < 4; a++)
#pragma unroll
        for (int j = 0; j < 4; j++) {
          int rowr = wm * 64 + a * 16 + hi * 4 + j;
          lds[rowr * 128 + colr] = f2bf((acc[a][b][j] + bv) * scl);
        }
    }
    __syncthreads();
    short* dstb = qkvb + (size_t)(tm * 256) * 2304 + tn * 128;
#pragma unroll
    for (int k = 0; k < 8; k++) {
      int g = k * 512 + tid;
      int r = g >> 4, c = g & 15;
      *(s16x8*)(dstb + (size_t)r * 2304 + c * 8) = *(const s16x8*)(lds + r * 128 + c * 8);
    }
  } else {
#pragma unroll
    for (int b = 0; b < 4; b++) {
      int coln = tn * 128 + wn * 64 + b * 16 + lo;
      float bv = bias[coln];
#pragma unroll
      for (int a = 0; a < 4; a++)
#pragma unroll
        for (int j = 0; j < 4; j++) {
          int rowm = tm * 256 + wm * 64 + a * 16 + hi * 4 + j;
          outf[(size_t)rowm * 768 + coln] = acc[a][b][j] + bv;
        }
    }
  }
}

// ---------------- attention (32x32 MFMA, sigma-permuted padded K; round-13) ----------------
// grid: 1024 blocks x 256 threads; pair = bid&127 (pair-major XCD swizzle),
// qt = bid>>7. 4 waves x 32 q-rows. Q pre-scaled into exp2 domain.
// K LDS [64][104] padded (bank-quad = (5*row+chunk) mod 8 -> <=2-way, free);
// sigma(key) = swap bits 2,3 row placement -> P->A-frag is lane-local packing.
// V LDS [96][64] XOR-chunk swizzled.

__global__ __launch_bounds__(256) void attn_kernel(const short* __restrict__ qkvb,
                                                   const short* __restrict__ vtb,
                                                   short* __restrict__ attn_out) {
  __shared__ short Klds[64 * 104];
  __shared__ short Vlds[96 * 64];
  int tid = threadIdx.x, lane = tid & 63, wid = tid >> 6;
  int q31 = lane & 31, hi2 = lane >> 5;
  int bid = blockIdx.x;
  int pair = bid & 127, qt = bid >> 7;
  int b = pair >> 3, h = pair & 7;
  const short* Vtp = vtb + (size_t)pair * 1024 * 96;  // [96][1024]
  int qrow0 = qt * 128 + wid * 32;

  s16x8 qf[6];
#pragma unroll
  for (int dc = 0; dc < 6; dc++)
    qf[dc] = *(const s16x8*)(qkvb + (size_t)(b * 1024 + qrow0 + q31) * 2304 +
                             h * 96 + dc * 16 + hi2 * 8);

  const short* sp[6];
  short* sdst[6];
  int sstep[6];
#pragma unroll
  for (int i = 0; i < 6; i++) {
    if (i < 3) {
      int c = i * 256 + tid;
      int krow = c / 12, kcc = c - krow * 12;
      int lam = swap23(krow);
      sdst[i] = Klds + lam * 104 + kcc * 8;
      sp[i] = qkvb + (size_t)(b * 1024 + krow) * 2304 + 768 + h * 96 + kcc * 8;
      sstep[i] = 64 * 2304;
    } else {
      int d = (i - 3) * 256 + tid;
      int vrow = d >> 3, vcc = d & 7;
      sdst[i] = Vlds + vrow * 64 + ((vcc ^ (vrow & 7)) << 3);
      sp[i] = Vtp + (size_t)vrow * 1024 + vcc * 8;
      sstep[i] = 64;
    }
  }

  f32x16 accO[3] = {};
  float lsum = 0.0f;

  s16x8 sreg[6];
#pragma unroll
  for (int i = 0; i < 6; i++) sreg[i] = *(const s16x8*)sp[i];

  for (int t = 0; t < 16; t++) {
    __syncthreads();
#pragma unroll
    for (int i = 0; i < 6; i++) *(s16x8*)sdst[i] = sreg[i];
    __syncthreads();

    int t2 = (t + 1) & 15;
#pragma unroll
    for (int i = 0; i < 6; i++)
      sreg[i] = *(const s16x8*)(sp[i] + (size_t)t2 * sstep[i]);

#pragma unroll
    for (int kb = 0; kb < 2; kb++) {
      f32x16 st = {};
#pragma unroll
      for (int dc = 0; dc < 6; dc++) {
        int c = dc * 2 + hi2;
        int lam = kb * 32 + q31;
        s16x8 kf = *(const s16x8*)(Klds + lam * 104 + c * 8);
        st = __builtin_amdgcn_mfma_f32_32x32x16_bf16(kf, qf[dc], st, 0, 0, 0);
      }

      unsigned u[8];
#pragma unroll
      for (int i = 0; i < 8; i++) {
        float p0 = __builtin_amdgcn_exp2f(st[2 * i]);
        float p1 = __builtin_amdgcn_exp2f(st[2 * i + 1]);
        unsigned w = pack2(p0, p1);
        u[i] = w;
        lsum += asf(w << 16) + asf(w & 0xffff0000u);
      }

#pragma unroll
      for (int half = 0; half < 2; half++) {
        union { unsigned w[4]; s16x8 v; } pa;
#pragma unroll
        for (int wi = 0; wi < 4; wi++) pa.w[wi] = u[half * 4 + wi];
        int kc = kb * 2 + half;
#pragma unroll
        for (int db = 0; db < 3; db++) {
          int d = db * 32 + q31;
          s16x8 vf = *(const s16x8*)(Vlds + d * 64 + (((kc * 2 + hi2) ^ (d & 7)) << 3));
          accO[db] = __builtin_amdgcn_mfma_f32_32x32x16_bf16(pa.v, vf, accO[db], 0, 0, 0);
        }
      }
    }
  }

  float s = lsum + __shfl_xor(lsum, 32, 64);
  float rinv = 1.0f / s;
  float rr[16];
#pragma unroll
  for (int r = 0; r < 16; r++)
    rr[r] = __shfl(rinv, (r & 3) + 8 * (r >> 2) + 4 * hi2, 64);

#pragma unroll
  for (int db = 0; db < 3; db++)
#pragma unroll
    for (int r = 0; r < 16; r++) {
      int qrow = qrow0 + (r & 3) + 8 * (r >> 2) + 4 * hi2;
      int d = db * 32 + q31;
      attn_out[((size_t)b * 1024 + qrow) * 768 + h * 96 + d] = f2bf(accO[db][r] * rr[r]);
    }
}

// ---------------- launch ----------------

extern "C" void kernel_launch(void* const* d_in, const int* in_sizes, int n_in,
                              void* d_out, int out_size, void* d_ws, size_t ws_size,
                              hipStream_t stream) {
  const float* x = (const float*)d_in[0];
  const float* Wqkv = (const float*)d_in[1];
  const float* bqkv = (const float*)d_in[2];
  const float* Wout = (const float*)d_in[3];
  const float* bout = (const float*)d_in[4];
  float* out = (float*)d_out;

  char* ws = (char*)d_ws;
  // layout (bytes), total 130,547,712:
  //   xb    @ 0          : 25,165,824  (bf16 x; later reused as attn_out [B][N][768])
  //   wqkvT @ 25165824   :  3,538,944
  //   woutT @ 28704768   :  1,179,648
  //   qkvb  @ 29884416   : 75,497,472  ([16384][2304] bf16)
  //   vtb   @ 105381888  : 25,165,824  ([pair][96][1024] bf16)
  short* xb = (short*)ws;
  short* wqkvT = (short*)(ws + 25165824);
  short* woutT = (short*)(ws + 28704768);
  short* qkvb = (short*)(ws + 29884416);
  short* vtb = (short*)(ws + 105381888);

  cvt_x_kernel<<<12288, 256, 0, stream>>>(x, xb);
  tcvt_kernel<<<dim3(72, 24), 256, 0, stream>>>(Wqkv, wqkvT, 768, 2304);
  tcvt_kernel<<<dim3(24, 24), 256, 0, stream>>>(Wout, woutT, 768, 768);

  // qkv: M=16384 (64 tiles), N=2304 (18 tiles) -> 1152 blocks (mult of 8)
  gemm2<0><<<1152, 512, 0, stream>>>(xb, wqkvT, bqkv, 768, 18, qkvb, nullptr);
  vtrans_kernel<<<dim3(3, 32, 128), 256, 0, stream>>>(qkvb, vtb);
  attn_kernel<<<1024, 256, 0, stream>>>(qkvb, vtb, xb);
  // out: M=16384 (64), N=768 (6) -> 384 blocks (mult of 8)
  gemm2<1><<<384, 512, 0, stream>>>(xb, woutT, bout, 768, 6, nullptr, out);
}

// Round 17
// 182.223 us; speedup vs baseline: 1.0367x; 1.0367x over previous
//
#include <hip/hip_runtime.h>
#include <hip/hip_bf16.h>

// Multi-head attention: x[16,1024,768] fp32, W_qkv[768,2304], b_qkv[2304],
// W_out[768,768], b_out[768] -> out[16,1024,768] fp32.
// Pipeline:
//   1) cvt_x: x -> bf16
//   2) tcvt:  W_qkv, W_out -> transposed bf16
//   3) gemm2<0>: qkv = x @ W_qkv + b; BM256xBN128xBK32, triple-buffered,
//      2 blocks/CU. Q/K tiles -> qkvb rows (coalesced); V tiles -> vtb
//      TRANSPOSED directly via per-wave LDS scratch (vtrans kernel deleted)
//   4) attn: 32x32 MFMA, sigma-permuted padded K LDS + setprio (T5)
//   5) gemm2<1>: out = attn @ W_out + b_out -> fp32

#define DEVINL __device__ __forceinline__

typedef __attribute__((ext_vector_type(8))) short s16x8;
typedef __attribute__((ext_vector_type(4))) short s16x4;
typedef __attribute__((ext_vector_type(4))) float f32x4;
typedef __attribute__((ext_vector_type(16))) float f32x16;

DEVINL short f2bf(float f) {
  union { float f; unsigned u; } c; c.f = f;
  unsigned r = c.u + 0x7FFFu + ((c.u >> 16) & 1u);
  return (short)(r >> 16);
}
DEVINL float asf(unsigned u) {
  union { unsigned u; float f; } c; c.u = u; return c.f;
}
// truncating pack (P-weights only; lsum uses the SAME truncated values)
DEVINL unsigned pack2(float a, float b) {
  union { float f; unsigned u; } ca, cb; ca.f = a; cb.f = b;
  return (ca.u >> 16) | (cb.u & 0xffff0000u);
}
DEVINL int swap23(int k) { return (k & ~12) | ((k & 4) << 1) | ((k & 8) >> 1); }

DEVINL void gload_lds16(const short* g, short* lds) {
  __builtin_amdgcn_global_load_lds((const __attribute__((address_space(1))) void*)g,
                                   (__attribute__((address_space(3))) void*)lds, 16, 0, 0);
}

// ---------------- conversion kernels ----------------

__global__ void cvt_x_kernel(const float* __restrict__ in, short* __restrict__ out) {
  int i = blockIdx.x * 256 + threadIdx.x;
  float4 v = ((const float4*)in)[i];
  s16x4 o = { f2bf(v.x), f2bf(v.y), f2bf(v.z), f2bf(v.w) };
  *(s16x4*)(out + (size_t)i * 4) = o;
}

__global__ void tcvt_kernel(const float* __restrict__ in, short* __restrict__ out, int R, int C) {
  __shared__ float t[32][33];
  int tx = threadIdx.x & 31, ty = threadIdx.x >> 5;
  int r0 = blockIdx.y * 32, c0 = blockIdx.x * 32;
#pragma unroll
  for (int i = 0; i < 4; i++) {
    int r = ty + i * 8;
    t[r][tx] = in[(size_t)(r0 + r) * C + c0 + tx];
  }
  __syncthreads();
#pragma unroll
  for (int i = 0; i < 4; i++) {
    int r = ty + i * 8;
    out[(size_t)(c0 + r) * R + r0 + tx] = f2bf(t[tx][r]);
  }
}

// ---------------- GEMM BM=256, BN=128, BK=32, 8 waves, 2 blocks/CU ----------------
// Triple-buffered (tile T staged during iteration T-2); one wait + one barrier
// per K-tile (round-15/16 verified, incl. tail drain).
// MODE 0 epilogue:
//   tn < 12 (Q/K): bias (+ q-scale incl log2e), [256][128] LDS relayout,
//                  coalesced b128 row stores to qkvb.
//   tn >= 12 (V):  bias; per-wave 64x64 transpose through 8KB LDS scratch
//                  (chunk swizzle c ^ ((n>>3&7)<<3): dump <=8-way, transpose
//                  reads conflict-FREE, derived), stored to vtb[pair][96][1024]
//                  as 128B-contiguous n-segments. qkvb V region never written.
// MODE 1: bias, fp32 [M][768] direct.

template <int MODE>
__global__ __launch_bounds__(512, 4) void gemm2(const short* __restrict__ A, const short* __restrict__ Bt,
                                                const float* __restrict__ bias, int K, int nTn,
                                                short* __restrict__ qkvb, short* __restrict__ vtb,
                                                float* __restrict__ outf) {
  __shared__ short lds[36864];          // 72KB: loop 3x24KB; epilogue relayout/scratch
  short* const ldsA = lds;              // [3 buf][2 q][4096]
  short* const ldsB = lds + 24576;      // [3 buf][4096]
  const int tid = threadIdx.x;
  const int l = tid & 63, w = tid >> 6;
  const int lo = l & 15, hi = l >> 4;
  const int wm = w >> 1, wn = w & 1;

  // XCD-aware bijective swizzle (gridDim.x % 8 == 0)
  int cpx = gridDim.x >> 3;
  int bid = blockIdx.x;
  int swz = (bid & 7) * cpx + (bid >> 3);
  int tm = swz / nTn, tn = swz - tm * nTn;

  const int NKT = K >> 5;

  // staging source (pair-swizzled): thread -> line L, slot s7
  const int Ls = tid >> 3, s7 = tid & 7;
  const int pS = (s7 >> 2) & 1;
  const int cS = (s7 & 3) ^ (Ls & 3);
  const int rho = 2 * Ls + pS;                      // region-row / col index [0,128)
  const int gA = ((rho >> 5) << 6) + (rho & 31);    // A row in tile (q adds +32)
  const short* aS0 = A + (size_t)(tm * 256 + gA) * K + cS * 8;
  const short* aS1 = aS0 + (size_t)32 * K;
  const short* bS = Bt + (size_t)(tn * 128 + rho) * K + cS * 8;

#define ST_A(j, q, bs) gload_lds16(((q) ? aS1 : aS0) + (j) * 32, ldsA + ((bs) * 2 + (q)) * 4096 + tid * 8)
#define ST_B(j, bs)    gload_lds16(bS + (j) * 32, ldsB + (bs) * 4096 + tid * 8)

  const int LaBase = wm * 16 + (lo >> 1);   // + mi*8
  const int LbBase = wn * 32 + (lo >> 1);   // + b*8
  const int pp = (lo & 1) << 2;

  f32x4 acc[4][4] = {};

#define RD_A(AF, bc, qm) do {                                                    \
    const short* base_ = ldsA + ((bc) * 2 + (qm)) * 4096;                        \
    _Pragma("unroll") for (int mi = 0; mi < 2; mi++) {                           \
      int La_ = LaBase + mi * 8;                                                 \
      AF[mi] = *(const s16x8*)(base_ + La_ * 64 + (((hi ^ (La_ & 3)) + pp) << 3)); } } while (0)
#define RD_B(BF, bc) do {                                                        \
    const short* base_ = ldsB + (bc) * 4096;                                     \
    _Pragma("unroll") for (int b = 0; b < 4; b++) {                              \
      int Lb_ = LbBase + b * 8;                                                  \
      BF[b] = *(const s16x8*)(base_ + Lb_ * 64 + (((hi ^ (Lb_ & 3)) + pp) << 3)); } } while (0)

#define MM8(a0, AF, BF) do {                                                     \
    __builtin_amdgcn_s_setprio(1);                                               \
    _Pragma("unroll") for (int mi = 0; mi < 2; mi++)                             \
      _Pragma("unroll") for (int b = 0; b < 4; b++)                              \
        acc[(a0) + mi][b] = __builtin_amdgcn_mfma_f32_16x16x32_bf16(             \
            AF[mi], BF[b], acc[(a0) + mi][b], 0, 0, 0);                          \
    __builtin_amdgcn_s_setprio(0); } while (0)

#define WAITV(n) asm volatile("s_waitcnt vmcnt(" #n ")" ::: "memory")
#define BARR() do { __builtin_amdgcn_sched_barrier(0); __builtin_amdgcn_s_barrier(); \
                    __builtin_amdgcn_sched_barrier(0); } while (0)

  // prologue: tiles 0 and 1 staged fully (tile order preserved for vmcnt)
  ST_A(0, 0, 0); ST_B(0, 0); ST_A(0, 1, 0);
  ST_A(1, 0, 1); ST_B(1, 1); ST_A(1, 1, 1);
  WAITV(3);      // tile 0's three loads retired
  __builtin_amdgcn_s_barrier();

  s16x8 af[2], bf[4];
  int bc = 0;
#pragma unroll 1
  for (int kt = 0; kt < NKT; kt++) {
    int bs = (bc == 0) ? 2 : bc - 1;        // (kt+2) % 3
    RD_A(af, bc, 0);
    RD_B(bf, bc);
    if (kt + 2 < NKT) { ST_A(kt + 2, 0, bs); ST_B(kt + 2, bs); }
    MM8(0, af, bf);
    RD_A(af, bc, 1);
    if (kt + 2 < NKT) ST_A(kt + 2, 1, bs);
    MM8(2, af, bf);
    if (kt + 2 < NKT) {
      WAITV(3);                 // retires tile kt+1's loads (3 newest = tile kt+2)
    } else if (kt + 2 == NKT) {
      WAITV(0);                 // tail: no newer loads; drain tile NKT-1 fully
    }
    BARR();
    bc = (bc == 2) ? 0 : bc + 1;
  }
#undef ST_A
#undef ST_B
#undef RD_A
#undef RD_B
#undef MM8
#undef WAITV
#undef BARR

  if (MODE == 0) {
    const float qscale = 0.14724444757204526f;  // 96^-0.5 * log2(e)
    __syncthreads();
    if (tn < 12) {
      // Q/K tiles: [256][128] relayout, coalesced row stores to qkvb
#pragma unroll
      for (int b = 0; b < 4; b++) {
        int colr = wn * 64 + b * 16 + lo;
        int coln = tn * 128 + colr;
        float bv = bias[coln];
        float scl = (coln < 768) ? qscale : 1.0f;
#pragma unroll
        for (int a = 0; a < 4; a++)
#pragma unroll
          for (int j = 0; j < 4; j++) {
            int rowr = wm * 64 + a * 16 + hi * 4 + j;
            lds[rowr * 128 + colr] = f2bf((acc[a][b][j] + bv) * scl);
          }
      }
      __syncthreads();
      short* dstb = qkvb + (size_t)(tm * 256) * 2304 + tn * 128;
#pragma unroll
      for (int k = 0; k < 8; k++) {
        int g = k * 512 + tid;
        int r = g >> 4, c = g & 15;
        *(s16x8*)(dstb + (size_t)r * 2304 + c * 8) = *(const s16x8*)(lds + r * 128 + c * 8);
      }
    } else {
      // V tiles: per-wave 64x64 transpose -> vtb[(b*8+h)*96+dd][1024 n]
      short* scr = lds + w * 4096;  // 8KB/wave, wave-private (no cross-wave sync)
#pragma unroll
      for (int b = 0; b < 4; b++) {
        int c = b * 16 + lo;
        float bv = bias[tn * 128 + wn * 64 + c];
#pragma unroll
        for (int a = 0; a < 4; a++)
#pragma unroll
          for (int j = 0; j < 4; j++) {
            int row = a * 16 + hi * 4 + j;                 // local n
            scr[row * 64 + (c ^ (((row >> 3) & 7) << 3))] = f2bf(acc[a][b][j] + bv);
          }
      }
      // transpose read (conflict-free by chunk swizzle) + 16B n-segment stores
      int r8 = l >> 3;            // 0..7: column sub-index within pass
      int k8 = l & 7;             // n-chunk: n0 = k8*8; (n>>3)&7 == k8 for j<8
      int n0 = k8 * 8;
      int rowg = tm * 256 + wm * 64;
      int bb = rowg >> 10;
      int nb = (rowg & 1023) + n0;
#pragma unroll
      for (int p = 0; p < 8; p++) {
        int c = p * 8 + r8;
        int inner = tn * 128 + wn * 64 + c - 1536;         // [0,768)
        int hh = inner / 96;
        int dd = inner - hh * 96;
        union { short v[8]; s16x8 x; } t;
#pragma unroll
        for (int j = 0; j < 8; j++)
          t.v[j] = scr[(n0 + j) * 64 + (c ^ (k8 << 3))];
        *(s16x8*)(vtb + ((size_t)(bb * 8 + hh) * 96 + dd) * 1024 + nb) = t.x;
      }
    }
  } else {
#pragma unroll
    for (int b = 0; b < 4; b++) {
      int coln = tn * 128 + wn * 64 + b * 16 + lo;
      float bv = bias[coln];
#pragma unroll
      for (int a = 0; a < 4; a++)
#pragma unroll
        for (int j = 0; j < 4; j++) {
          int rowm = tm * 256 + wm * 64 + a * 16 + hi * 4 + j;
          outf[(size_t)rowm * 768 + coln] = acc[a][b][j] + bv;
        }
    }
  }
}

// ---------------- attention (32x32 MFMA, sigma-permuted padded K; round-13 + T5) ----------------
// grid: 1024 blocks x 256 threads; pair = bid&127 (pair-major XCD swizzle),
// qt = bid>>7. 4 waves x 32 q-rows. Q pre-scaled into exp2 domain.
// K LDS [64][104] padded (<=2-way); sigma(key)=swap bits 2,3 -> P->A-frag
// lane-local. V LDS [96][64] XOR-chunk. setprio(1) around MFMA clusters (T5).

__global__ __launch_bounds__(256) void attn_kernel(const short* __restrict__ qkvb,
                                                   const short* __restrict__ vtb,
                                                   short* __restrict__ attn_out) {
  __shared__ short Klds[64 * 104];
  __shared__ short Vlds[96 * 64];
  int tid = threadIdx.x, lane = tid & 63, wid = tid >> 6;
  int q31 = lane & 31, hi2 = lane >> 5;
  int bid = blockIdx.x;
  int pair = bid & 127, qt = bid >> 7;
  int b = pair >> 3, h = pair & 7;
  const short* Vtp = vtb + (size_t)pair * 1024 * 96;  // [96][1024]
  int qrow0 = qt * 128 + wid * 32;

  s16x8 qf[6];
#pragma unroll
  for (int dc = 0; dc < 6; dc++)
    qf[dc] = *(const s16x8*)(qkvb + (size_t)(b * 1024 + qrow0 + q31) * 2304 +
                             h * 96 + dc * 16 + hi2 * 8);

  const short* sp[6];
  short* sdst[6];
  int sstep[6];
#pragma unroll
  for (int i = 0; i < 6; i++) {
    if (i < 3) {
      int c = i * 256 + tid;
      int krow = c / 12, kcc = c - krow * 12;
      int lam = swap23(krow);
      sdst[i] = Klds + lam * 104 + kcc * 8;
      sp[i] = qkvb + (size_t)(b * 1024 + krow) * 2304 + 768 + h * 96 + kcc * 8;
      sstep[i] = 64 * 2304;
    } else {
      int d = (i - 3) * 256 + tid;
      int vrow = d >> 3, vcc = d & 7;
      sdst[i] = Vlds + vrow * 64 + ((vcc ^ (vrow & 7)) << 3);
      sp[i] = Vtp + (size_t)vrow * 1024 + vcc * 8;
      sstep[i] = 64;
    }
  }

  f32x16 accO[3] = {};
  float lsum = 0.0f;

  s16x8 sreg[6];
#pragma unroll
  for (int i = 0; i < 6; i++) sreg[i] = *(const s16x8*)sp[i];

  for (int t = 0; t < 16; t++) {
    __syncthreads();
#pragma unroll
    for (int i = 0; i < 6; i++) *(s16x8*)sdst[i] = sreg[i];
    __syncthreads();

    int t2 = (t + 1) & 15;
#pragma unroll
    for (int i = 0; i < 6; i++)
      sreg[i] = *(const s16x8*)(sp[i] + (size_t)t2 * sstep[i]);

#pragma unroll
    for (int kb = 0; kb < 2; kb++) {
      f32x16 st = {};
      __builtin_amdgcn_s_setprio(1);
#pragma unroll
      for (int dc = 0; dc < 6; dc++) {
        int c = dc * 2 + hi2;
        int lam = kb * 32 + q31;
        s16x8 kf = *(const s16x8*)(Klds + lam * 104 + c * 8);
        st = __builtin_amdgcn_mfma_f32_32x32x16_bf16(kf, qf[dc], st, 0, 0, 0);
      }
      __builtin_amdgcn_s_setprio(0);

      unsigned u[8];
#pragma unroll
      for (int i = 0; i < 8; i++) {
        float p0 = __builtin_amdgcn_exp2f(st[2 * i]);
        float p1 = __builtin_amdgcn_exp2f(st[2 * i + 1]);
        unsigned w = pack2(p0, p1);
        u[i] = w;
        lsum += asf(w << 16) + asf(w & 0xffff0000u);
      }

      __builtin_amdgcn_s_setprio(1);
#pragma unroll
      for (int half = 0; half < 2; half++) {
        union { unsigned w[4]; s16x8 v; } pa;
#pragma unroll
        for (int wi = 0; wi < 4; wi++) pa.w[wi] = u[half * 4 + wi];
        int kc = kb * 2 + half;
#pragma unroll
        for (int db = 0; db < 3; db++) {
          int d = db * 32 + q31;
          s16x8 vf = *(const s16x8*)(Vlds + d * 64 + (((kc * 2 + hi2) ^ (d & 7)) << 3));
          accO[db] = __builtin_amdgcn_mfma_f32_32x32x16_bf16(pa.v, vf, accO[db], 0, 0, 0);
        }
      }
      __builtin_amdgcn_s_setprio(0);
    }
  }

  float s = lsum + __shfl_xor(lsum, 32, 64);
  float rinv = 1.0f / s;
  float rr[16];
#pragma unroll
  for (int r = 0; r < 16; r++)
    rr[r] = __shfl(rinv, (r & 3) + 8 * (r >> 2) + 4 * hi2, 64);

#pragma unroll
  for (int db = 0; db < 3; db++)
#pragma unroll
    for (int r = 0; r < 16; r++) {
      int qrow = qrow0 + (r & 3) + 8 * (r >> 2) + 4 * hi2;
      int d = db * 32 + q31;
      attn_out[((size_t)b * 1024 + qrow) * 768 + h * 96 + d] = f2bf(accO[db][r] * rr[r]);
    }
}

// ---------------- launch ----------------

extern "C" void kernel_launch(void* const* d_in, const int* in_sizes, int n_in,
                              void* d_out, int out_size, void* d_ws, size_t ws_size,
                              hipStream_t stream) {
  const float* x = (const float*)d_in[0];
  const float* Wqkv = (const float*)d_in[1];
  const float* bqkv = (const float*)d_in[2];
  const float* Wout = (const float*)d_in[3];
  const float* bout = (const float*)d_in[4];
  float* out = (float*)d_out;

  char* ws = (char*)d_ws;
  // layout (bytes), total 130,547,712:
  //   xb    @ 0          : 25,165,824  (bf16 x; later reused as attn_out [B][N][768])
  //   wqkvT @ 25165824   :  3,538,944
  //   woutT @ 28704768   :  1,179,648
  //   qkvb  @ 29884416   : 75,497,472  ([16384][2304] bf16; V region unused)
  //   vtb   @ 105381888  : 25,165,824  ([pair][96][1024] bf16)
  short* xb = (short*)ws;
  short* wqkvT = (short*)(ws + 25165824);
  short* woutT = (short*)(ws + 28704768);
  short* qkvb = (short*)(ws + 29884416);
  short* vtb = (short*)(ws + 105381888);

  cvt_x_kernel<<<12288, 256, 0, stream>>>(x, xb);
  tcvt_kernel<<<dim3(72, 24), 256, 0, stream>>>(Wqkv, wqkvT, 768, 2304);
  tcvt_kernel<<<dim3(24, 24), 256, 0, stream>>>(Wout, woutT, 768, 768);

  // qkv: M=16384 (64 tiles), N=2304 (18 tiles) -> 1152 blocks (mult of 8)
  gemm2<0><<<1152, 512, 0, stream>>>(xb, wqkvT, bqkv, 768, 18, qkvb, vtb, nullptr);
  attn_kernel<<<1024, 256, 0, stream>>>(qkvb, vtb, xb);
  // out: M=16384 (64), N=768 (6) -> 384 blocks (mult of 8)
  gemm2<1><<<384, 512, 0, stream>>>(xb, woutT, bout, 768, 6, nullptr, nullptr, out);
}